// Round 1
// baseline (878.440 us; speedup 1.0000x reference)
//
#include <hip/hip_runtime.h>

// StepRelu: y = 0                       if x <= 0
//           y = (ceil(x/0.1)-1)*0.1     if 0 < x <= 1.6
//           y = x                       if x > 1.6
// Memory-bound elementwise over 2^27 fp32 (512 MiB in + 512 MiB out, > L3).
// R2 change: grid-stride with capped grid (2048 blocks) + 4-deep unroll.
//   - 4 nontemporal loads in flight per wave (MLP) instead of 1-shot blocks
//   - stride = gridDim*blockDim keeps every instruction fully coalesced
//     (64 lanes x 16 B = 1 KiB contiguous per wave per instruction)
//   - 131072 -> 2048 workgroup dispatches
// Plain fp32 division kept to match numpy's ceil(x/theta) bin edges exactly
// (absmax 0.0 verified in the previous session).

typedef float vfloat4 __attribute__((ext_vector_type(4)));

__device__ __forceinline__ float step_relu_1(float x) {
    const float theta = 0.1f;
    const float upper = theta * 16.0f;           // == 1.6000000238418579f
    float binned = (ceilf(x / theta) - 1.0f) * theta;
    float y = (x <= upper) ? binned : x;
    return (x <= 0.0f) ? 0.0f : y;
}

__device__ __forceinline__ vfloat4 step_relu_4(vfloat4 v) {
    vfloat4 r;
    r.x = step_relu_1(v.x);
    r.y = step_relu_1(v.y);
    r.z = step_relu_1(v.z);
    r.w = step_relu_1(v.w);
    return r;
}

__global__ __launch_bounds__(256) void step_relu_kernel(
    const vfloat4* __restrict__ in, vfloat4* __restrict__ out, int n4) {
    const int stride = gridDim.x * blockDim.x;
    int i = blockIdx.x * blockDim.x + threadIdx.x;

    // 4-deep unrolled grid-stride: issue 4 independent nt loads, then
    // compute+store. Compiler schedules loads ahead of first use (vmcnt>0).
    for (; i + 3 * stride < n4; i += 4 * stride) {
        vfloat4 v0 = __builtin_nontemporal_load(&in[i]);
        vfloat4 v1 = __builtin_nontemporal_load(&in[i + stride]);
        vfloat4 v2 = __builtin_nontemporal_load(&in[i + 2 * stride]);
        vfloat4 v3 = __builtin_nontemporal_load(&in[i + 3 * stride]);
        __builtin_nontemporal_store(step_relu_4(v0), &out[i]);
        __builtin_nontemporal_store(step_relu_4(v1), &out[i + stride]);
        __builtin_nontemporal_store(step_relu_4(v2), &out[i + 2 * stride]);
        __builtin_nontemporal_store(step_relu_4(v3), &out[i + 3 * stride]);
    }
    for (; i < n4; i += stride) {
        vfloat4 v = __builtin_nontemporal_load(&in[i]);
        __builtin_nontemporal_store(step_relu_4(v), &out[i]);
    }
}

__global__ __launch_bounds__(256) void step_relu_tail(
    const float* __restrict__ in, float* __restrict__ out, int start, int n) {
    int i = start + blockIdx.x * blockDim.x + threadIdx.x;
    if (i < n) out[i] = step_relu_1(in[i]);
}

extern "C" void kernel_launch(void* const* d_in, const int* in_sizes, int n_in,
                              void* d_out, int out_size, void* d_ws, size_t ws_size,
                              hipStream_t stream) {
    const float* x = (const float*)d_in[0];
    float* y = (float*)d_out;
    int n = in_sizes[0];

    int n4 = n / 4;
    if (n4 > 0) {
        int blocks = (n4 + 255) / 256;
        if (blocks > 2048) blocks = 2048;   // ~8 blocks/CU, grid-stride the rest
        step_relu_kernel<<<blocks, 256, 0, stream>>>(
            (const vfloat4*)x, (vfloat4*)y, n4);
    }
    int rem = n - n4 * 4;
    if (rem > 0) {
        step_relu_tail<<<1, 256, 0, stream>>>(x, y, n4 * 4, n);
    }
}

// Round 2
// 820.307 us; speedup vs baseline: 1.0709x; 1.0709x over previous
//
#include <hip/hip_runtime.h>

// StepRelu: y = 0                       if x <= 0
//           y = (ceil(x/0.1)-1)*0.1     if 0 < x <= 1.6
//           y = x                       if x > 1.6
// Memory-bound elementwise over 2^27 fp32 (512 MiB in + 512 MiB out, > L3).
//
// R3: REVERT the capped-grid strided loop (R2, +81 us regression — scattered
// active footprint thrashed DRAM row buffers). Back to the one-shot compact
// sweep that measured 797.5 us, with a block-local 2-deep unroll:
//   - each block covers a contiguous 8 KiB window (2 x 256 vfloat4)
//   - thread t handles base+t and base+t+256 -> 2 nt-loads in flight
//   - resident blocks form a compact sliding window over the stream
//     (dispatch is ~blockIdx-ordered), preserving row-buffer locality
//   - 131072 -> 65536 workgroup launches
// Plain fp32 division kept to match numpy's ceil(x/theta) bin edges exactly
// (absmax 0.0 verified).

typedef float vfloat4 __attribute__((ext_vector_type(4)));

__device__ __forceinline__ float step_relu_1(float x) {
    const float theta = 0.1f;
    const float upper = theta * 16.0f;           // == 1.6000000238418579f
    float binned = (ceilf(x / theta) - 1.0f) * theta;
    float y = (x <= upper) ? binned : x;
    return (x <= 0.0f) ? 0.0f : y;
}

__device__ __forceinline__ vfloat4 step_relu_4(vfloat4 v) {
    vfloat4 r;
    r.x = step_relu_1(v.x);
    r.y = step_relu_1(v.y);
    r.z = step_relu_1(v.z);
    r.w = step_relu_1(v.w);
    return r;
}

__global__ __launch_bounds__(256) void step_relu_kernel(
    const vfloat4* __restrict__ in, vfloat4* __restrict__ out, int n4) {
    int i0 = blockIdx.x * (2 * 256) + threadIdx.x;   // block owns 512 vfloat4
    int i1 = i0 + 256;
    if (i1 < n4) {
        // common path: both loads issued back-to-back (2 in flight)
        vfloat4 v0 = __builtin_nontemporal_load(&in[i0]);
        vfloat4 v1 = __builtin_nontemporal_load(&in[i1]);
        __builtin_nontemporal_store(step_relu_4(v0), &out[i0]);
        __builtin_nontemporal_store(step_relu_4(v1), &out[i1]);
    } else if (i0 < n4) {
        vfloat4 v0 = __builtin_nontemporal_load(&in[i0]);
        __builtin_nontemporal_store(step_relu_4(v0), &out[i0]);
    }
}

__global__ __launch_bounds__(256) void step_relu_tail(
    const float* __restrict__ in, float* __restrict__ out, int start, int n) {
    int i = start + blockIdx.x * blockDim.x + threadIdx.x;
    if (i < n) out[i] = step_relu_1(in[i]);
}

extern "C" void kernel_launch(void* const* d_in, const int* in_sizes, int n_in,
                              void* d_out, int out_size, void* d_ws, size_t ws_size,
                              hipStream_t stream) {
    const float* x = (const float*)d_in[0];
    float* y = (float*)d_out;
    int n = in_sizes[0];

    int n4 = n / 4;
    if (n4 > 0) {
        int per_block = 512;                          // 2 vfloat4 per thread
        int blocks = (n4 + per_block - 1) / per_block;
        step_relu_kernel<<<blocks, 256, 0, stream>>>(
            (const vfloat4*)x, (vfloat4*)y, n4);
    }
    int rem = n - n4 * 4;
    if (rem > 0) {
        step_relu_tail<<<1, 256, 0, stream>>>(x, y, n4 * 4, n);
    }
}